// Round 3
// baseline (10301.492 us; speedup 1.0000x reference)
//
#include <hip/hip_runtime.h>
#include <math.h>

#define NN 512
#define DD 8192

// ---------------- row-norm scales: scale[m][r] = 1 / max(||row||, 1e-6) ----------------
__global__ __launch_bounds__(256) void norm_kernel(
    const float* __restrict__ a0, const float* __restrict__ a1,
    const float* __restrict__ a2, float* __restrict__ scales) {
  const float* mats[3] = {a0, a1, a2};
  const int m = blockIdx.y;
  const int row = blockIdx.x;
  const float* x = mats[m] + (size_t)row * DD;
  const int tid = threadIdx.x;
  float s = 0.f;
  for (int k = tid * 4; k < DD; k += 256 * 4) {
    const float4 v = *(const float4*)(x + k);
    s += v.x * v.x + v.y * v.y + v.z * v.z + v.w * v.w;
  }
#pragma unroll
  for (int off = 32; off > 0; off >>= 1) s += __shfl_down(s, off);
  __shared__ float ws[4];
  if ((tid & 63) == 0) ws[tid >> 6] = s;
  __syncthreads();
  if (tid == 0) {
    const float t = ws[0] + ws[1] + ws[2] + ws[3];
    scales[m * NN + row] = 1.0f / fmaxf(sqrtf(t), 1e-6f);
  }
}

// ---------------- cost_p = 1 - (A B^T) * sa * sb, p: (0:1->2, 1:2->3, 2:3->1) ----------
__global__ __launch_bounds__(256) void cost_gemm_kernel(
    const float* __restrict__ a0, const float* __restrict__ a1,
    const float* __restrict__ a2, const float* __restrict__ scales,
    float* __restrict__ cost_all) {
  const float* mats[3] = {a0, a1, a2};
  const int p = blockIdx.z;
  const int pA = p, pB = (p + 1) % 3;
  const float* A = mats[pA];
  const float* B = mats[pB];
  float* C = cost_all + (size_t)p * NN * NN;

  __shared__ float lds_a[32 * 64];
  __shared__ float lds_b[32 * 64];

  const int tid = threadIdx.x;
  const int rowBase = blockIdx.y * 64;
  const int colBase = blockIdx.x * 64;

  const int lr = tid & 63;   // row within tile for staging
  const int lq = tid >> 6;   // 0..3

  const float* Arow = A + (size_t)(rowBase + lr) * DD;
  const float* Brow = B + (size_t)(colBase + lr) * DD;

  float acc[4][4];
#pragma unroll
  for (int i = 0; i < 4; ++i)
#pragma unroll
    for (int j = 0; j < 4; ++j) acc[i][j] = 0.f;

  const int tx = tid & 15, ty = tid >> 4;

  for (int kb = 0; kb < DD; kb += 32) {
#pragma unroll
    for (int qq = 0; qq < 2; ++qq) {
      const int q = lq + qq * 4;  // 0..7, covers k offsets q*4..q*4+3
      const float4 av = *(const float4*)(Arow + kb + q * 4);
      const float4 bv = *(const float4*)(Brow + kb + q * 4);
      lds_a[(q * 4 + 0) * 64 + lr] = av.x;
      lds_a[(q * 4 + 1) * 64 + lr] = av.y;
      lds_a[(q * 4 + 2) * 64 + lr] = av.z;
      lds_a[(q * 4 + 3) * 64 + lr] = av.w;
      lds_b[(q * 4 + 0) * 64 + lr] = bv.x;
      lds_b[(q * 4 + 1) * 64 + lr] = bv.y;
      lds_b[(q * 4 + 2) * 64 + lr] = bv.z;
      lds_b[(q * 4 + 3) * 64 + lr] = bv.w;
    }
    __syncthreads();
#pragma unroll
    for (int k = 0; k < 32; ++k) {
      const float4 a4 = *(const float4*)(&lds_a[k * 64 + ty * 4]);
      const float4 b4 = *(const float4*)(&lds_b[k * 64 + tx * 4]);
      const float as0[4] = {a4.x, a4.y, a4.z, a4.w};
      const float bs0[4] = {b4.x, b4.y, b4.z, b4.w};
#pragma unroll
      for (int ii = 0; ii < 4; ++ii)
#pragma unroll
        for (int jj = 0; jj < 4; ++jj)
          acc[ii][jj] = fmaf(as0[ii], bs0[jj], acc[ii][jj]);
    }
    __syncthreads();
  }

#pragma unroll
  for (int ii = 0; ii < 4; ++ii) {
    const int gr = rowBase + ty * 4 + ii;
    const float sa = scales[pA * NN + gr];
#pragma unroll
    for (int jj = 0; jj < 4; ++jj) {
      const int gc = colBase + tx * 4 + jj;
      const float sb = scales[pB * NN + gc];
      C[gr * NN + gc] = 1.0f - acc[ii][jj] * sa * sb;
    }
  }
}

// ---------------- exact JV shortest-augmenting-path LAP, SINGLE WAVE per problem -------
// 64 lanes, lane owns columns j = q*64+lane (q=0..7). The Dijkstra inner loop has NO
// cross-lane LDS dependencies (all cross-lane via shfl); LDS handoffs only at phase
// boundaries, fenced with __syncthreads (nearly free for a 1-wave block, but required
// as a compiler memory fence — removing them miscompiled in R2).
// f64 duals, reference-identical arithmetic order and argmin tie-breaking.
__global__ __launch_bounds__(64) void lap_kernel(
    const float* __restrict__ cost_all, float* __restrict__ out) {
  const int p = blockIdx.x;
  const float* __restrict__ cost = cost_all + (size_t)p * NN * NN;
  float* __restrict__ outp = out + (size_t)p * NN * NN;
  const int lane = threadIdx.x;  // 0..63

  __shared__ double sh_u[NN];
  __shared__ double sh_enter[NN];   // broadcast minval at the moment row entered SR
  __shared__ int sh_path[NN];
  __shared__ int sh_col4row[NN];
  __shared__ int sh_row4col[NN];
  __shared__ int sh_SRlist[NN];

  const double INF = __builtin_inf();

  double v[8];       // v[j] for owned columns
  double shortest[8];
  int rc[8];         // register mirror of sh_row4col for owned columns

#pragma unroll
  for (int q = 0; q < 8; ++q) {
    const int j = q * 64 + lane;
    sh_u[j] = 0.0;
    sh_col4row[j] = -1;
    sh_row4col[j] = -1;
    v[q] = 0.0;
    rc[q] = -1;
  }
  __syncthreads();

  for (int cur_row = 0; cur_row < NN; ++cur_row) {
    int scMask = 0;
#pragma unroll
    for (int q = 0; q < 8; ++q) shortest[q] = INF;

    int i = cur_row;
    double minv = 0.0;
    int nSR = 0;
    int sink = -1;

    // ---- Dijkstra inner loop: barrier-free (shfl-only cross-lane traffic) ----
    while (true) {
      const double u_i = sh_u[i];  // broadcast LDS read (written only at phase boundary)
      const float* rp = cost + (i << 9) + lane;
      float c[8];
#pragma unroll
      for (int q = 0; q < 8; ++q) c[q] = rp[q << 6];

      double best = INF;
      int bj = 0x7fffffff;
      int brow = -1;
#pragma unroll
      for (int q = 0; q < 8; ++q) {
        if (!(scMask & (1 << q))) {
          const double r = minv + (double)c[q] - u_i - v[q];
          if (r < shortest[q]) {
            shortest[q] = r;
            sh_path[q * 64 + lane] = i;  // own slot; read only after the loop (fenced)
          }
          if (shortest[q] < best) {  // ascending q => smallest j among this lane's ties
            best = shortest[q];
            bj = q * 64 + lane;
            brow = rc[q];
          }
        }
      }
      // butterfly argmin across 64 lanes, payload (best, j, row4col[j]); tie -> smaller j
#pragma unroll
      for (int off = 1; off < 64; off <<= 1) {
        const double ov = __shfl_xor(best, off);
        const int oj = __shfl_xor(bj, off);
        const int orow = __shfl_xor(brow, off);
        if (ov < best || (ov == best && oj < bj)) { best = ov; bj = oj; brow = orow; }
      }
      minv = best;
      if ((bj & 63) == lane) scMask |= 1 << (bj >> 6);  // mark SC (freezes shortest[q])
      if (brow < 0) { sink = bj; break; }
      // row brow enters SR via column bj; record its entry value (== shortest[col4row[brow]])
      if (lane == 0) { sh_enter[brow] = best; sh_SRlist[nSR] = brow; }
      nSR++;  // wave-uniform
      i = brow;
    }

    __syncthreads();  // fence: sh_path / sh_enter / sh_SRlist now visible to all lanes

    // dual updates (before augmentation, like the reference)
    for (int t = lane; t < nSR; t += 64) {
      const int r = sh_SRlist[t];
      sh_u[r] += minv - sh_enter[r];   // == minv - shortest[col4row[r]]
    }
    if (lane == 0) sh_u[cur_row] += minv;
#pragma unroll
    for (int q = 0; q < 8; ++q) {
      if (scMask & (1 << q)) v[q] -= minv - shortest[q];
    }

    // augment along alternating path (short chain, serial on lane 0)
    if (lane == 0) {
      int j = sink;
      while (true) {
        const int ii = sh_path[j];
        sh_row4col[j] = ii;
        const int tmp = sh_col4row[ii];
        sh_col4row[ii] = j;
        j = tmp;
        if (ii == cur_row) break;
      }
    }
    __syncthreads();  // fence: sh_row4col / sh_col4row / sh_u visible before next phase

    // refresh register mirror of row4col for owned columns
#pragma unroll
    for (int q = 0; q < 8; ++q) rc[q] = sh_row4col[q * 64 + lane];
  }

#pragma unroll
  for (int q = 0; q < 8; ++q) {
    const int r = q * 64 + lane;
    outp[(size_t)r * NN + sh_col4row[r]] = 1.0f;
  }
}

extern "C" void kernel_launch(void* const* d_in, const int* in_sizes, int n_in,
                              void* d_out, int out_size, void* d_ws, size_t ws_size,
                              hipStream_t stream) {
  const float* un1 = (const float*)d_in[0];
  const float* un2 = (const float*)d_in[1];
  const float* un3 = (const float*)d_in[2];
  float* out = (float*)d_out;

  float* cost = (float*)d_ws;                       // 3 * 512 * 512 floats
  float* scales = cost + (size_t)3 * NN * NN;       // 3 * 512 floats

  hipMemsetAsync(d_out, 0, (size_t)out_size * sizeof(float), stream);

  norm_kernel<<<dim3(NN, 3), 256, 0, stream>>>(un1, un2, un3, scales);
  cost_gemm_kernel<<<dim3(NN / 64, NN / 64, 3), 256, 0, stream>>>(un1, un2, un3, scales, cost);
  lap_kernel<<<3, NN / 8, 0, stream>>>(cost, out);
}